// Round 2
// baseline (468.230 us; speedup 1.0000x reference)
//
#include <hip/hip_runtime.h>
#include <hip/hip_bf16.h>

#define HID 1024
#define SEQ 4096
#define NBATCH 4

typedef __attribute__((ext_vector_type(8))) short bf16x8;
typedef __attribute__((ext_vector_type(4))) float f32x4;

__device__ __forceinline__ unsigned short f2bf(float f) {
  union { float f; unsigned u; } v; v.f = f;
  unsigned r = v.u + 0x7fffu + ((v.u >> 16) & 1u);
  return (unsigned short)(r >> 16);
}
__device__ __forceinline__ float bf2f(unsigned short h) {
  union { unsigned u; float f; } v; v.u = ((unsigned)h) << 16; return v.f;
}
__device__ __forceinline__ void gload16(const void* g, void* l) {
  __builtin_amdgcn_global_load_lds(
      (const __attribute__((address_space(1))) unsigned*)g,
      (__attribute__((address_space(3))) unsigned*)l, 16, 0, 0);
}

// ---------- split x into hi/lo bf16 ----------
__global__ __launch_bounds__(256) void split_x_kernel(
    const float* __restrict__ x, unsigned short* __restrict__ xhi,
    unsigned short* __restrict__ xlo) {
  const int i = blockIdx.x * 256 + threadIdx.x;
  const float4 v = ((const float4*)x)[i];
  const float f[4] = {v.x, v.y, v.z, v.w};
  unsigned short hh[4], ll[4];
#pragma unroll
  for (int j = 0; j < 4; ++j) {
    const unsigned short hb = f2bf(f[j]);
    hh[j] = hb;
    ll[j] = f2bf(f[j] - bf2f(hb));
  }
  ushort4 h, l;
  h.x = hh[0]; h.y = hh[1]; h.z = hh[2]; h.w = hh[3];
  l.x = ll[0]; l.y = ll[1]; l.z = ll[2]; l.w = ll[3];
  ((ushort4*)xhi)[i] = h;
  ((ushort4*)xlo)[i] = l;
}

// ---------- transpose + split weights: dst[n][k] = W[k][n] ----------
__global__ __launch_bounds__(256) void split_w_kernel(
    const float* __restrict__ Wq, const float* __restrict__ Wk,
    const float* __restrict__ Wv, const float* __restrict__ Wo,
    unsigned short* qh, unsigned short* ql, unsigned short* kh,
    unsigned short* kl, unsigned short* vh, unsigned short* oh) {
  const float* W; unsigned short* dh; unsigned short* dl;
  if (blockIdx.z == 0)      { W = Wq; dh = qh; dl = ql; }
  else if (blockIdx.z == 1) { W = Wk; dh = kh; dl = kl; }
  else if (blockIdx.z == 2) { W = Wv; dh = vh; dl = nullptr; }
  else                      { W = Wo; dh = oh; dl = nullptr; }
  __shared__ float t[32][33];
  const int tx = threadIdx.x & 31, ty = threadIdx.x >> 5;
  const int c0 = blockIdx.x * 32, r0 = blockIdx.y * 32;
#pragma unroll
  for (int i = 0; i < 32; i += 8)
    t[ty + i][tx] = W[(size_t)(r0 + ty + i) * HID + c0 + tx];
  __syncthreads();
#pragma unroll
  for (int i = 0; i < 32; i += 8) {
    const float f = t[tx][ty + i];  // = W[r0+tx][c0+ty+i]
    const size_t di = (size_t)(c0 + ty + i) * HID + (r0 + tx);
    const unsigned short hb = f2bf(f);
    dh[di] = hb;
    if (dl) dl[di] = f2bf(f - bf2f(hb));
  }
}

// ---------- GEMM: C[z] = A[z] @ B^T-layout (B stored [N][K]) ----------
// SPLIT3: acc = A1*B1 + A1*B2 + A2*B1 (hi/lo split precision)
template <bool SPLIT3, bool OUT_BF16, bool BIAS>
__global__ __launch_bounds__(256, 2) void gemm_kernel(
    const unsigned short* __restrict__ A1, const unsigned short* __restrict__ A2,
    const unsigned short* __restrict__ B1, const unsigned short* __restrict__ B2,
    float* __restrict__ Cf, unsigned short* __restrict__ Cb,
    const float* __restrict__ bias, int M, int N, int Kd) {
  constexpr int TILE = 128 * 32;  // ushorts per tile (8 KB)
  constexpr int NT = SPLIT3 ? 4 : 2;
  __shared__ unsigned short lds[NT * TILE];
  unsigned short* As1 = lds;
  unsigned short* Bs1 = lds + TILE;
  unsigned short* As2 = SPLIT3 ? lds + 2 * TILE : nullptr;
  unsigned short* Bs2 = SPLIT3 ? lds + 3 * TILE : nullptr;

  const int tid = threadIdx.x;
  const int lane = tid & 63;
  const int w = tid >> 6;
  const int wr = w >> 1, wc = w & 1;
  const int m0 = blockIdx.x * 128, n0 = blockIdx.y * 128;
  const int z = blockIdx.z;

  const unsigned short* pA1 = A1 + (size_t)z * M * Kd;
  const unsigned short* pA2 = SPLIT3 ? A2 + (size_t)z * M * Kd : nullptr;

  f32x4 acc[4][4] = {};

  const int fr = lane & 15;
  const int k8 = (lane >> 4) * 8;

  for (int kt = 0; kt < Kd; kt += 32) {
#pragma unroll
    for (int i = 0; i < 2; ++i) {
      const int ob = i * 4096 + tid * 16;  // byte offset within tile
      const int r = ob >> 6;
      const int ce = (ob & 63) >> 1;  // element col (0,8,16,24)
      gload16(pA1 + (size_t)(m0 + r) * Kd + kt + ce, (char*)As1 + ob);
      gload16(B1 + (size_t)(n0 + r) * Kd + kt + ce, (char*)Bs1 + ob);
      if (SPLIT3) {
        gload16(pA2 + (size_t)(m0 + r) * Kd + kt + ce, (char*)As2 + ob);
        gload16(B2 + (size_t)(n0 + r) * Kd + kt + ce, (char*)Bs2 + ob);
      }
    }
    __syncthreads();
    bf16x8 a1[4], b1[4], a2[4], b2[4];
#pragma unroll
    for (int m = 0; m < 4; ++m) {
      const int row = wr * 64 + m * 16 + fr;
      a1[m] = *(const bf16x8*)&As1[row * 32 + k8];
      if (SPLIT3) a2[m] = *(const bf16x8*)&As2[row * 32 + k8];
    }
#pragma unroll
    for (int n = 0; n < 4; ++n) {
      const int row = wc * 64 + n * 16 + fr;
      b1[n] = *(const bf16x8*)&Bs1[row * 32 + k8];
      if (SPLIT3) b2[n] = *(const bf16x8*)&Bs2[row * 32 + k8];
    }
#pragma unroll
    for (int m = 0; m < 4; ++m)
#pragma unroll
      for (int n = 0; n < 4; ++n) {
        acc[m][n] = __builtin_amdgcn_mfma_f32_16x16x32_bf16(a1[m], b1[n], acc[m][n], 0, 0, 0);
        if (SPLIT3) {
          acc[m][n] = __builtin_amdgcn_mfma_f32_16x16x32_bf16(a1[m], b2[n], acc[m][n], 0, 0, 0);
          acc[m][n] = __builtin_amdgcn_mfma_f32_16x16x32_bf16(a2[m], b1[n], acc[m][n], 0, 0, 0);
        }
      }
    __syncthreads();
  }

  const int r4 = (lane >> 4) * 4;
#pragma unroll
  for (int m = 0; m < 4; ++m) {
    const int row0 = m0 + wr * 64 + m * 16 + r4;
#pragma unroll
    for (int n = 0; n < 4; ++n) {
      const int col = n0 + wc * 64 + n * 16 + fr;
      const float bv = BIAS ? bias[col] : 0.0f;
#pragma unroll
      for (int r2 = 0; r2 < 4; ++r2) {
        const size_t idx = (size_t)z * M * N + (size_t)(row0 + r2) * N + col;
        const float vv = acc[m][n][r2] + bv;
        if (OUT_BF16) Cb[idx] = f2bf(vv);
        else Cf[idx] = vv;
      }
    }
  }
}

// ---------- energy[n,a,b] = sum_{s,d} Q[n,s,a*64+d] * K[n,s,b*64+d] ----------
__global__ __launch_bounds__(256) void energy_kernel(
    const float* __restrict__ Q, const float* __restrict__ Kq,
    float* __restrict__ energy) {
  const int n = blockIdx.y;
  const int s0 = blockIdx.x * 32;
  __shared__ float qs[16 * 68];
  __shared__ float ks[16 * 68];
  const int tid = threadIdx.x;
  const int a = tid >> 4, b = tid & 15;
  const int hb = (tid * 4) >> 6, d0 = (tid * 4) & 63;
  const float* Qn = Q + (size_t)n * SEQ * HID;
  const float* Kn = Kq + (size_t)n * SEQ * HID;
  float acc = 0.0f;
  for (int s = s0; s < s0 + 32; ++s) {
    __syncthreads();
    const float4 q4 = ((const float4*)(Qn + (size_t)s * HID))[tid];
    const float4 k4 = ((const float4*)(Kn + (size_t)s * HID))[tid];
    float* qp = qs + hb * 68 + d0;
    qp[0] = q4.x; qp[1] = q4.y; qp[2] = q4.z; qp[3] = q4.w;
    float* kp = ks + hb * 68 + d0;
    kp[0] = k4.x; kp[1] = k4.y; kp[2] = k4.z; kp[3] = k4.w;
    __syncthreads();
    float dot = 0.0f;
#pragma unroll
    for (int d = 0; d < 64; ++d) dot += qs[a * 68 + d] * ks[b * 68 + d];
    acc += dot;
  }
  atomicAdd(&energy[n * 256 + a * 16 + b], acc);
}

// ---------- softmax over b for each (n,a) row of 16 ----------
__global__ void softmax_kernel(const float* __restrict__ energy,
                               float* __restrict__ att) {
  const int t = threadIdx.x;  // 64 threads = (n,a)
  const float* e = energy + t * 16;
  float m = -3.0e38f;
#pragma unroll
  for (int b = 0; b < 16; ++b) m = fmaxf(m, e[b]);
  float p[16];
  float ssum = 0.0f;
#pragma unroll
  for (int b = 0; b < 16; ++b) { p[b] = expf((e[b] - m) * 0.125f); ssum += p[b]; }
  const float inv = 1.0f / ssum;
#pragma unroll
  for (int b = 0; b < 16; ++b) att[t * 16 + b] = p[b] * inv;
}

// ---------- out2[n, h*256+sg, r*64+d] = sum_b att[n,h,b] V[n, sg*16+r, b*64+d] ----------
__global__ __launch_bounds__(256) void out2_kernel(
    const unsigned short* __restrict__ V, const float* __restrict__ att,
    unsigned short* __restrict__ out2) {
  const int n = blockIdx.y, sg = blockIdx.x;
  __shared__ unsigned short vl[16 * 1032];  // padded stride vs bank conflicts
  __shared__ float al[256];
  const int tid = threadIdx.x;
  al[tid] = att[n * 256 + tid];
  const unsigned short* Vbp = V + ((size_t)n * SEQ + (size_t)sg * 16) * HID;
#pragma unroll
  for (int j = 0; j < 16; ++j) {
    const ushort4 u = *(const ushort4*)(Vbp + (size_t)j * HID + tid * 4);
    *(ushort4*)&vl[j * 1032 + tid * 4] = u;
  }
  __syncthreads();
  const int c0 = tid * 4;
  const int rr = c0 >> 6, d = c0 & 63;
  float vb[16][4];
#pragma unroll
  for (int b = 0; b < 16; ++b)
#pragma unroll
    for (int j = 0; j < 4; ++j)
      vb[b][j] = bf2f(vl[rr * 1032 + b * 64 + d + j]);
#pragma unroll
  for (int h = 0; h < 16; ++h) {
    float o0 = 0, o1 = 0, o2 = 0, o3 = 0;
#pragma unroll
    for (int b = 0; b < 16; ++b) {
      const float wgt = al[h * 16 + b];
      o0 += wgt * vb[b][0]; o1 += wgt * vb[b][1];
      o2 += wgt * vb[b][2]; o3 += wgt * vb[b][3];
    }
    ushort4 u;
    u.x = f2bf(o0); u.y = f2bf(o1); u.z = f2bf(o2); u.w = f2bf(o3);
    *(ushort4*)(out2 + ((size_t)n * SEQ + (size_t)(h * 256 + sg)) * HID + c0) = u;
  }
}

extern "C" void kernel_launch(void* const* d_in, const int* in_sizes, int n_in,
                              void* d_out, int out_size, void* d_ws, size_t ws_size,
                              hipStream_t stream) {
  (void)in_sizes; (void)n_in; (void)out_size; (void)ws_size;
  const float* x  = (const float*)d_in[0];
  const float* Wq = (const float*)d_in[1];
  const float* Wk = (const float*)d_in[2];
  const float* Wv = (const float*)d_in[3];
  const float* Wo = (const float*)d_in[4];
  const float* bo = (const float*)d_in[5];
  float* out = (float*)d_out;

  char* ws = (char*)d_ws;
  size_t off = 0;
  auto alloc = [&](size_t bytes) {
    char* p = ws + off;
    off += (bytes + 255) & ~(size_t)255;
    return p;
  };
  const size_t XE = (size_t)NBATCH * SEQ * HID;
  unsigned short* Xhi = (unsigned short*)alloc(XE * 2);
  unsigned short* Xlo = (unsigned short*)alloc(XE * 2);  // aliased by Vb later
  unsigned short* WqhT = (unsigned short*)alloc((size_t)HID * HID * 2);
  unsigned short* WqlT = (unsigned short*)alloc((size_t)HID * HID * 2);
  unsigned short* WkhT = (unsigned short*)alloc((size_t)HID * HID * 2);
  unsigned short* WklT = (unsigned short*)alloc((size_t)HID * HID * 2);
  unsigned short* WvhT = (unsigned short*)alloc((size_t)HID * HID * 2);
  unsigned short* WohT = (unsigned short*)alloc((size_t)HID * HID * 2);
  float* Q  = (float*)alloc(XE * 4);  // aliased by O2 later
  float* Kf = (float*)alloc(XE * 4);
  float* energy = (float*)alloc((size_t)NBATCH * 256 * 4);
  float* att    = (float*)alloc((size_t)NBATCH * 256 * 4);
  // Aliases (stream-order safe):
  //   Vb  overlays Xlo: Xlo's last reader is the K-GEMM; V-GEMM (writer of Vb)
  //       runs after it and reads only Xhi/WvhT.
  //   O2  overlays Q:   Q's last reader is energy_kernel; out2 (writer of O2)
  //       runs after softmax; final GEMM reads O2 + WohT only.
  unsigned short* Vb = (unsigned short*)Xlo;
  unsigned short* O2 = (unsigned short*)Q;

  split_x_kernel<<<(unsigned)(XE / 4 / 256), 256, 0, stream>>>(x, Xhi, Xlo);
  split_w_kernel<<<dim3(HID / 32, HID / 32, 4), 256, 0, stream>>>(
      Wq, Wk, Wv, Wo, WqhT, WqlT, WkhT, WklT, WvhT, WohT);

  dim3 gg(SEQ / 128, HID / 128, NBATCH);
  gemm_kernel<true, false, false><<<gg, 256, 0, stream>>>(
      Xhi, Xlo, WqhT, WqlT, Q, nullptr, nullptr, SEQ, HID, HID);
  gemm_kernel<true, false, false><<<gg, 256, 0, stream>>>(
      Xhi, Xlo, WkhT, WklT, Kf, nullptr, nullptr, SEQ, HID, HID);
  gemm_kernel<false, true, false><<<gg, 256, 0, stream>>>(
      Xhi, nullptr, WvhT, nullptr, nullptr, Vb, nullptr, SEQ, HID, HID);

  hipMemsetAsync(energy, 0, (size_t)NBATCH * 256 * 4, stream);
  energy_kernel<<<dim3(SEQ / 32, NBATCH), 256, 0, stream>>>(Q, Kf, energy);
  softmax_kernel<<<1, 64, 0, stream>>>(energy, att);
  out2_kernel<<<dim3(256, NBATCH), 256, 0, stream>>>(Vb, att, O2);

  gemm_kernel<false, false, true><<<gg, 256, 0, stream>>>(
      O2, nullptr, WohT, nullptr, out, nullptr, bo, SEQ, HID, HID);
}

// Round 3
// 439.944 us; speedup vs baseline: 1.0643x; 1.0643x over previous
//
#include <hip/hip_runtime.h>
#include <hip/hip_bf16.h>

#define HID 1024
#define SEQ 4096
#define NBATCH 4

typedef __attribute__((ext_vector_type(8))) short bf16x8;
typedef __attribute__((ext_vector_type(4))) float f32x4;

__device__ __forceinline__ unsigned short f2bf(float f) {
  union { float f; unsigned u; } v; v.f = f;
  unsigned r = v.u + 0x7fffu + ((v.u >> 16) & 1u);
  return (unsigned short)(r >> 16);
}
__device__ __forceinline__ float bf2f(unsigned short h) {
  union { unsigned u; float f; } v; v.u = ((unsigned)h) << 16; return v.f;
}
__device__ __forceinline__ void gload16(const void* g, void* l) {
  __builtin_amdgcn_global_load_lds(
      (const __attribute__((address_space(1))) unsigned*)g,
      (__attribute__((address_space(3))) unsigned*)l, 16, 0, 0);
}

// ---------- split x: straight hi (for V-GEMM) + transposed hi/lo (for Gram) ----------
// x [N][SEQ][HID] -> xhi [N][SEQ][HID], xthi/xtlo [N][HID][SEQ]
__global__ __launch_bounds__(256) void split_x_kernel(
    const float* __restrict__ x, unsigned short* __restrict__ xhi,
    unsigned short* __restrict__ xthi, unsigned short* __restrict__ xtlo) {
  const int n = blockIdx.z;
  const int c0 = blockIdx.x * 32;  // HID col
  const int s0 = blockIdx.y * 32;  // seq row
  __shared__ float t[32][33];
  const int tx = threadIdx.x & 31, ty = threadIdx.x >> 5;
  const float* xp = x + (size_t)n * SEQ * HID;
#pragma unroll
  for (int i = 0; i < 32; i += 8) {
    const float f = xp[(size_t)(s0 + ty + i) * HID + c0 + tx];
    t[ty + i][tx] = f;
    xhi[(size_t)n * SEQ * HID + (size_t)(s0 + ty + i) * HID + c0 + tx] = f2bf(f);
  }
  __syncthreads();
#pragma unroll
  for (int i = 0; i < 32; i += 8) {
    const float f = t[tx][ty + i];  // = x[s0+tx][c0+ty+i]
    const size_t di = (size_t)n * HID * SEQ + (size_t)(c0 + ty + i) * SEQ + s0 + tx;
    const unsigned short hb = f2bf(f);
    xthi[di] = hb;
    xtlo[di] = f2bf(f - bf2f(hb));
  }
}

// ---------- transpose + split weights: dst[n][k] = W[k][n] ----------
// z=0: Wq (hi+lo), z=1: Wv (hi), z=2: Wo (hi)
__global__ __launch_bounds__(256) void split_w_kernel(
    const float* __restrict__ Wq, const float* __restrict__ Wv,
    const float* __restrict__ Wo, unsigned short* qh, unsigned short* ql,
    unsigned short* vh, unsigned short* oh) {
  const float* W; unsigned short* dh; unsigned short* dl;
  if (blockIdx.z == 0)      { W = Wq; dh = qh; dl = ql; }
  else if (blockIdx.z == 1) { W = Wv; dh = vh; dl = nullptr; }
  else                      { W = Wo; dh = oh; dl = nullptr; }
  __shared__ float t[32][33];
  const int tx = threadIdx.x & 31, ty = threadIdx.x >> 5;
  const int c0 = blockIdx.x * 32, r0 = blockIdx.y * 32;
#pragma unroll
  for (int i = 0; i < 32; i += 8)
    t[ty + i][tx] = W[(size_t)(r0 + ty + i) * HID + c0 + tx];
  __syncthreads();
#pragma unroll
  for (int i = 0; i < 32; i += 8) {
    const float f = t[tx][ty + i];  // = W[r0+tx][c0+ty+i]
    const size_t di = (size_t)(c0 + ty + i) * HID + (r0 + tx);
    const unsigned short hb = f2bf(f);
    dh[di] = hb;
    if (dl) dl[di] = f2bf(f - bf2f(hb));
  }
}

// ---------- GEMM: C[z] = A[z] @ B^T-layout (B stored [N][K], shared over z) ----------
// SPLIT3: acc = A1*B1 + A1*B2 + A2*B1 (hi/lo split precision)
template <bool SPLIT3, bool OUT_BF16, bool BIAS>
__global__ __launch_bounds__(256, 2) void gemm_kernel(
    const unsigned short* __restrict__ A1, const unsigned short* __restrict__ A2,
    const unsigned short* __restrict__ B1, const unsigned short* __restrict__ B2,
    float* __restrict__ Cf, unsigned short* __restrict__ Cb,
    const float* __restrict__ bias, int M, int N, int Kd) {
  constexpr int TILE = 128 * 32;  // ushorts per tile (8 KB)
  constexpr int NT = SPLIT3 ? 4 : 2;
  __shared__ unsigned short lds[NT * TILE];
  unsigned short* As1 = lds;
  unsigned short* Bs1 = lds + TILE;
  unsigned short* As2 = SPLIT3 ? lds + 2 * TILE : nullptr;
  unsigned short* Bs2 = SPLIT3 ? lds + 3 * TILE : nullptr;

  const int tid = threadIdx.x;
  const int lane = tid & 63;
  const int w = tid >> 6;
  const int wr = w >> 1, wc = w & 1;
  const int m0 = blockIdx.x * 128, n0 = blockIdx.y * 128;
  const int z = blockIdx.z;

  const unsigned short* pA1 = A1 + (size_t)z * M * Kd;
  const unsigned short* pA2 = SPLIT3 ? A2 + (size_t)z * M * Kd : nullptr;

  f32x4 acc[4][4] = {};

  const int fr = lane & 15;
  const int k8 = (lane >> 4) * 8;

  for (int kt = 0; kt < Kd; kt += 32) {
#pragma unroll
    for (int i = 0; i < 2; ++i) {
      const int ob = i * 4096 + tid * 16;  // byte offset within tile
      const int r = ob >> 6;
      const int ce = (ob & 63) >> 1;  // element col (0,8,16,24)
      gload16(pA1 + (size_t)(m0 + r) * Kd + kt + ce, (char*)As1 + ob);
      gload16(B1 + (size_t)(n0 + r) * Kd + kt + ce, (char*)Bs1 + ob);
      if (SPLIT3) {
        gload16(pA2 + (size_t)(m0 + r) * Kd + kt + ce, (char*)As2 + ob);
        gload16(B2 + (size_t)(n0 + r) * Kd + kt + ce, (char*)Bs2 + ob);
      }
    }
    __syncthreads();
    bf16x8 a1[4], b1[4], a2[4], b2[4];
#pragma unroll
    for (int m = 0; m < 4; ++m) {
      const int row = wr * 64 + m * 16 + fr;
      a1[m] = *(const bf16x8*)&As1[row * 32 + k8];
      if (SPLIT3) a2[m] = *(const bf16x8*)&As2[row * 32 + k8];
    }
#pragma unroll
    for (int n = 0; n < 4; ++n) {
      const int row = wc * 64 + n * 16 + fr;
      b1[n] = *(const bf16x8*)&Bs1[row * 32 + k8];
      if (SPLIT3) b2[n] = *(const bf16x8*)&Bs2[row * 32 + k8];
    }
#pragma unroll
    for (int m = 0; m < 4; ++m)
#pragma unroll
      for (int n = 0; n < 4; ++n) {
        acc[m][n] = __builtin_amdgcn_mfma_f32_16x16x32_bf16(a1[m], b1[n], acc[m][n], 0, 0, 0);
        if (SPLIT3) {
          acc[m][n] = __builtin_amdgcn_mfma_f32_16x16x32_bf16(a1[m], b2[n], acc[m][n], 0, 0, 0);
          acc[m][n] = __builtin_amdgcn_mfma_f32_16x16x32_bf16(a2[m], b1[n], acc[m][n], 0, 0, 0);
        }
      }
    __syncthreads();
  }

  const int r4 = (lane >> 4) * 4;
#pragma unroll
  for (int m = 0; m < 4; ++m) {
    const int row0 = m0 + wr * 64 + m * 16 + r4;
#pragma unroll
    for (int n = 0; n < 4; ++n) {
      const int col = n0 + wc * 64 + n * 16 + fr;
      const float bv = BIAS ? bias[col] : 0.0f;
#pragma unroll
      for (int r2 = 0; r2 < 4; ++r2) {
        const size_t idx = (size_t)z * M * N + (size_t)(row0 + r2) * N + col;
        const float vv = acc[m][n][r2] + bv;
        if (OUT_BF16) Cb[idx] = f2bf(vv);
        else Cf[idx] = vv;
      }
    }
  }
}

// ---------- Gram: Gpart[chunk][n] = Xt[n][:, chunk*2048 +: 2048] @ itself^T (split3) ----------
// Xt layout [N][HID][SEQ]; C[m,c] = sum_k Xt[m,k]*Xt[c,k]
__global__ __launch_bounds__(256, 2) void gram_kernel(
    const unsigned short* __restrict__ Xthi, const unsigned short* __restrict__ Xtlo,
    float* __restrict__ Gpart) {
  constexpr int TILE = 128 * 32;
  __shared__ unsigned short lds[4 * TILE];
  unsigned short* As1 = lds;
  unsigned short* Bs1 = lds + TILE;
  unsigned short* As2 = lds + 2 * TILE;
  unsigned short* Bs2 = lds + 3 * TILE;

  const int tid = threadIdx.x;
  const int lane = tid & 63;
  const int w = tid >> 6;
  const int wr = w >> 1, wc = w & 1;
  const int m0 = blockIdx.x * 128, n0 = blockIdx.y * 128;
  const int nb = blockIdx.z >> 1, chunk = blockIdx.z & 1;

  const size_t abase = (size_t)nb * HID * SEQ + (size_t)chunk * 2048;
  const unsigned short* pH = Xthi + abase;  // row stride SEQ
  const unsigned short* pL = Xtlo + abase;

  f32x4 acc[4][4] = {};
  const int fr = lane & 15;
  const int k8 = (lane >> 4) * 8;

  for (int kt = 0; kt < 2048; kt += 32) {
#pragma unroll
    for (int i = 0; i < 2; ++i) {
      const int ob = i * 4096 + tid * 16;
      const int r = ob >> 6;
      const int ce = (ob & 63) >> 1;
      gload16(pH + (size_t)(m0 + r) * SEQ + kt + ce, (char*)As1 + ob);
      gload16(pH + (size_t)(n0 + r) * SEQ + kt + ce, (char*)Bs1 + ob);
      gload16(pL + (size_t)(m0 + r) * SEQ + kt + ce, (char*)As2 + ob);
      gload16(pL + (size_t)(n0 + r) * SEQ + kt + ce, (char*)Bs2 + ob);
    }
    __syncthreads();
    bf16x8 a1[4], b1[4], a2[4], b2[4];
#pragma unroll
    for (int m = 0; m < 4; ++m) {
      const int row = wr * 64 + m * 16 + fr;
      a1[m] = *(const bf16x8*)&As1[row * 32 + k8];
      a2[m] = *(const bf16x8*)&As2[row * 32 + k8];
    }
#pragma unroll
    for (int n = 0; n < 4; ++n) {
      const int row = wc * 64 + n * 16 + fr;
      b1[n] = *(const bf16x8*)&Bs1[row * 32 + k8];
      b2[n] = *(const bf16x8*)&Bs2[row * 32 + k8];
    }
#pragma unroll
    for (int m = 0; m < 4; ++m)
#pragma unroll
      for (int n = 0; n < 4; ++n) {
        acc[m][n] = __builtin_amdgcn_mfma_f32_16x16x32_bf16(a1[m], b1[n], acc[m][n], 0, 0, 0);
        acc[m][n] = __builtin_amdgcn_mfma_f32_16x16x32_bf16(a1[m], b2[n], acc[m][n], 0, 0, 0);
        acc[m][n] = __builtin_amdgcn_mfma_f32_16x16x32_bf16(a2[m], b1[n], acc[m][n], 0, 0, 0);
      }
    __syncthreads();
  }

  float* Cf = Gpart + ((size_t)chunk * NBATCH + nb) * HID * HID;
  const int r4 = (lane >> 4) * 4;
#pragma unroll
  for (int m = 0; m < 4; ++m) {
    const int row0 = m0 + wr * 64 + m * 16 + r4;
#pragma unroll
    for (int n = 0; n < 4; ++n) {
      const int col = n0 + wc * 64 + n * 16 + fr;
#pragma unroll
      for (int r2 = 0; r2 < 4; ++r2)
        Cf[(size_t)(row0 + r2) * HID + col] = acc[m][n][r2];
    }
  }
}

// ---------- reduce K-split partials + split G into hi/lo bf16 ----------
__global__ __launch_bounds__(256) void reduce_split_kernel(
    const float* __restrict__ Gp, unsigned short* __restrict__ ghi,
    unsigned short* __restrict__ glo) {
  const size_t i = ((size_t)blockIdx.x * 256 + threadIdx.x) * 4;
  const float4 a = *(const float4*)(Gp + i);
  const float4 b = *(const float4*)(Gp + i + (size_t)NBATCH * HID * HID);
  const float f[4] = {a.x + b.x, a.y + b.y, a.z + b.z, a.w + b.w};
  ushort4 h, l;
  unsigned short hh[4], ll[4];
#pragma unroll
  for (int j = 0; j < 4; ++j) {
    hh[j] = f2bf(f[j]);
    ll[j] = f2bf(f[j] - bf2f(hh[j]));
  }
  h.x = hh[0]; h.y = hh[1]; h.z = hh[2]; h.w = hh[3];
  l.x = ll[0]; l.y = ll[1]; l.z = ll[2]; l.w = ll[3];
  *(ushort4*)(ghi + i) = h;
  *(ushort4*)(glo + i) = l;
}

// ---------- energy-style reduction: E[n,a,b] = sum_{r,d} Q[n,r,a*64+d]*K[n,r,b*64+d] ----------
// rows per batch = grid.x*32; both operands have 1024 cols; kstride=0 => K shared
__global__ __launch_bounds__(256) void energy_kernel(
    const float* __restrict__ Q, const float* __restrict__ Kq,
    float* __restrict__ energy, size_t qstride, size_t kstride) {
  const int n = blockIdx.y;
  const int s0 = blockIdx.x * 32;
  __shared__ float qs[16 * 68];
  __shared__ float ks[16 * 68];
  const int tid = threadIdx.x;
  const int a = tid >> 4, b = tid & 15;
  const int hb = (tid * 4) >> 6, d0 = (tid * 4) & 63;
  const float* Qn = Q + (size_t)n * qstride;
  const float* Kn = Kq + (size_t)n * kstride;
  float acc = 0.0f;
  for (int s = s0; s < s0 + 32; ++s) {
    __syncthreads();
    const float4 q4 = ((const float4*)(Qn + (size_t)s * HID))[tid];
    const float4 k4 = ((const float4*)(Kn + (size_t)s * HID))[tid];
    float* qp = qs + hb * 68 + d0;
    qp[0] = q4.x; qp[1] = q4.y; qp[2] = q4.z; qp[3] = q4.w;
    float* kp = ks + hb * 68 + d0;
    kp[0] = k4.x; kp[1] = k4.y; kp[2] = k4.z; kp[3] = k4.w;
    __syncthreads();
    float dot = 0.0f;
#pragma unroll
    for (int d = 0; d < 64; ++d) dot += qs[a * 68 + d] * ks[b * 68 + d];
    acc += dot;
  }
  atomicAdd(&energy[n * 256 + a * 16 + b], acc);
}

// ---------- softmax over b for each (n,a) row of 16 ----------
__global__ void softmax_kernel(const float* __restrict__ energy,
                               float* __restrict__ att) {
  const int t = threadIdx.x;  // 64 threads = (n,a)
  const float* e = energy + t * 16;
  float m = -3.0e38f;
#pragma unroll
  for (int b = 0; b < 16; ++b) m = fmaxf(m, e[b]);
  float p[16];
  float ssum = 0.0f;
#pragma unroll
  for (int b = 0; b < 16; ++b) { p[b] = expf((e[b] - m) * 0.125f); ssum += p[b]; }
  const float inv = 1.0f / ssum;
#pragma unroll
  for (int b = 0; b < 16; ++b) att[t * 16 + b] = p[b] * inv;
}

// ---------- out2[n, h*256+sg, r*64+d] = sum_b att[n,h,b] V[n, sg*16+r, b*64+d] ----------
__global__ __launch_bounds__(256) void out2_kernel(
    const unsigned short* __restrict__ V, const float* __restrict__ att,
    unsigned short* __restrict__ out2) {
  const int n = blockIdx.y, sg = blockIdx.x;
  __shared__ unsigned short vl[16 * 1032];
  __shared__ float al[256];
  const int tid = threadIdx.x;
  al[tid] = att[n * 256 + tid];
  const unsigned short* Vbp = V + ((size_t)n * SEQ + (size_t)sg * 16) * HID;
#pragma unroll
  for (int j = 0; j < 16; ++j) {
    const ushort4 u = *(const ushort4*)(Vbp + (size_t)j * HID + tid * 4);
    *(ushort4*)&vl[j * 1032 + tid * 4] = u;
  }
  __syncthreads();
  const int c0 = tid * 4;
  const int rr = c0 >> 6, d = c0 & 63;
  float vb[16][4];
#pragma unroll
  for (int b = 0; b < 16; ++b)
#pragma unroll
    for (int j = 0; j < 4; ++j)
      vb[b][j] = bf2f(vl[rr * 1032 + b * 64 + d + j]);
#pragma unroll
  for (int h = 0; h < 16; ++h) {
    float o0 = 0, o1 = 0, o2 = 0, o3 = 0;
#pragma unroll
    for (int b = 0; b < 16; ++b) {
      const float wgt = al[h * 16 + b];
      o0 += wgt * vb[b][0]; o1 += wgt * vb[b][1];
      o2 += wgt * vb[b][2]; o3 += wgt * vb[b][3];
    }
    ushort4 u;
    u.x = f2bf(o0); u.y = f2bf(o1); u.z = f2bf(o2); u.w = f2bf(o3);
    *(ushort4*)(out2 + ((size_t)n * SEQ + (size_t)(h * 256 + sg)) * HID + c0) = u;
  }
}

extern "C" void kernel_launch(void* const* d_in, const int* in_sizes, int n_in,
                              void* d_out, int out_size, void* d_ws, size_t ws_size,
                              hipStream_t stream) {
  (void)in_sizes; (void)n_in; (void)out_size; (void)ws_size;
  const float* x  = (const float*)d_in[0];
  const float* Wq = (const float*)d_in[1];
  const float* Wk = (const float*)d_in[2];
  const float* Wv = (const float*)d_in[3];
  const float* Wo = (const float*)d_in[4];
  const float* bo = (const float*)d_in[5];
  float* out = (float*)d_out;

  char* ws = (char*)d_ws;
  size_t off = 0;
  auto alloc = [&](size_t bytes) {
    char* p = ws + off;
    off += (bytes + 255) & ~(size_t)255;
    return p;
  };
  const size_t XE = (size_t)NBATCH * SEQ * HID;   // 16.8M elems
  const size_t GE = (size_t)NBATCH * HID * HID;   // 4.2M elems
  unsigned short* Xhi  = (unsigned short*)alloc(XE * 2);  // straight, for V-GEMM
  unsigned short* Xthi = (unsigned short*)alloc(XE * 2);  // transposed hi (-> Vb later)
  unsigned short* Xtlo = (unsigned short*)alloc(XE * 2);  // transposed lo (-> O2 later)
  unsigned short* WqhT = (unsigned short*)alloc((size_t)HID * HID * 2);
  unsigned short* WqlT = (unsigned short*)alloc((size_t)HID * HID * 2);
  unsigned short* WvhT = (unsigned short*)alloc((size_t)HID * HID * 2);
  unsigned short* WohT = (unsigned short*)alloc((size_t)HID * HID * 2);
  float* Gpart = (float*)alloc(2 * GE * 4);               // K-split partials (-> M1 later)
  unsigned short* Ghi = (unsigned short*)alloc(GE * 2);
  unsigned short* Glo = (unsigned short*)alloc(GE * 2);
  float* energy = (float*)alloc((size_t)NBATCH * 256 * 4);
  float* att    = (float*)alloc((size_t)NBATCH * 256 * 4);
  // Stream-order-safe aliases:
  //   Vb overlays Xthi (last read: gram). M1 overlays Gpart (last read: reduce_split).
  //   O2 overlays Xtlo (last read: gram).
  unsigned short* Vb = Xthi;
  float* M1 = Gpart;
  unsigned short* O2 = Xtlo;

  split_x_kernel<<<dim3(HID / 32, SEQ / 32, NBATCH), 256, 0, stream>>>(
      x, Xhi, Xthi, Xtlo);
  split_w_kernel<<<dim3(HID / 32, HID / 32, 3), 256, 0, stream>>>(
      Wq, Wv, Wo, WqhT, WqlT, WvhT, WohT);

  // G = X^T X per batch, split3, K-split 2 (512 blocks = 2/CU)
  gram_kernel<<<dim3(HID / 128, HID / 128, NBATCH * 2), 256, 0, stream>>>(
      Xthi, Xtlo, Gpart);
  reduce_split_kernel<<<(unsigned)(GE / 4 / 256), 256, 0, stream>>>(
      Gpart, Ghi, Glo);

  // V = X @ Wv (plain bf16) — writes Vb (aliases Xthi, dead after gram)
  gemm_kernel<false, true, false><<<dim3(SEQ / 128, HID / 128, NBATCH), 256, 0, stream>>>(
      Xhi, nullptr, WvhT, nullptr, nullptr, Vb, nullptr, SEQ, HID, HID);

  // M1 = G @ Wq (split3; G symmetric so rows of G are A directly)
  gemm_kernel<true, false, false><<<dim3(HID / 128, HID / 128, NBATCH), 256, 0, stream>>>(
      Ghi, Glo, WqhT, WqlT, M1, nullptr, nullptr, HID, HID, HID);

  // E[n,a,b] = sum_{k',d} M1[n,k',a64+d] * Wk[k',b64+d]
  hipMemsetAsync(energy, 0, (size_t)NBATCH * 256 * 4, stream);
  energy_kernel<<<dim3(HID / 32, NBATCH), 256, 0, stream>>>(
      M1, Wk, energy, (size_t)HID * HID, 0);
  softmax_kernel<<<1, 64, 0, stream>>>(energy, att);
  out2_kernel<<<dim3(256, NBATCH), 256, 0, stream>>>(Vb, att, O2);

  gemm_kernel<false, false, true><<<dim3(SEQ / 128, HID / 128, NBATCH), 256, 0, stream>>>(
      O2, nullptr, WohT, nullptr, out, nullptr, bo, SEQ, HID, HID);
}

// Round 5
// 427.827 us; speedup vs baseline: 1.0944x; 1.0283x over previous
//
#include <hip/hip_runtime.h>
#include <hip/hip_bf16.h>

#define HID 1024
#define SEQ 4096
#define NBATCH 4

typedef __attribute__((ext_vector_type(8))) short bf16x8;
typedef __attribute__((ext_vector_type(4))) float f32x4;
typedef __attribute__((ext_vector_type(8))) unsigned short u16x8;

__device__ __forceinline__ unsigned short f2bf(float f) {
  union { float f; unsigned u; } v; v.f = f;
  unsigned r = v.u + 0x7fffu + ((v.u >> 16) & 1u);
  return (unsigned short)(r >> 16);
}
__device__ __forceinline__ float bf2f(unsigned short h) {
  union { unsigned u; float f; } v; v.u = ((unsigned)h) << 16; return v.f;
}
__device__ __forceinline__ void gload16(const void* g, void* l) {
  __builtin_amdgcn_global_load_lds(
      (const __attribute__((address_space(1))) unsigned*)g,
      (__attribute__((address_space(3))) unsigned*)l, 16, 0, 0);
}

// ---------- split x: straight hi (V-GEMM) + transposed hi/lo (Gram) ----------
// x [N][SEQ][HID] -> xhi [N][SEQ][HID], xthi/xtlo [N][HID][SEQ]
// 64x64 tile per block; float4 reads, ushort4 straight writes, ushort8
// transposed writes. LDS stride 65 -> 2-way (free) banks on the read path.
__global__ __launch_bounds__(256) void split_x_kernel(
    const float* __restrict__ x, unsigned short* __restrict__ xhi,
    unsigned short* __restrict__ xthi, unsigned short* __restrict__ xtlo) {
  const int n = blockIdx.z;
  const int c0 = blockIdx.x * 64;  // HID
  const int s0 = blockIdx.y * 64;  // seq
  __shared__ float t[64][65];
  const int tid = threadIdx.x;
  const int rr = tid >> 4;          // 0..15
  const int cc = (tid & 15) * 4;    // 0..60
  const float* xp = x + (size_t)n * SEQ * HID;
  unsigned short* xhp = xhi + (size_t)n * SEQ * HID;
#pragma unroll
  for (int p = 0; p < 4; ++p) {
    const int row = rr + p * 16;
    const float4 v = *(const float4*)(xp + (size_t)(s0 + row) * HID + c0 + cc);
    t[row][cc] = v.x; t[row][cc + 1] = v.y; t[row][cc + 2] = v.z; t[row][cc + 3] = v.w;
    ushort4 h;
    h.x = f2bf(v.x); h.y = f2bf(v.y); h.z = f2bf(v.z); h.w = f2bf(v.w);
    *(ushort4*)(xhp + (size_t)(s0 + row) * HID + c0 + cc) = h;
  }
  __syncthreads();
  const int c = tid >> 2;           // 0..63 (col within tile)
  const int sb = (tid & 3) * 16;    // 0,16,32,48 (seq chunk)
  const size_t tbase = (size_t)n * HID * SEQ + (size_t)(c0 + c) * SEQ + s0 + sb;
  unsigned short hbuf[16] __attribute__((aligned(16)));
  unsigned short lbuf[16] __attribute__((aligned(16)));
#pragma unroll
  for (int k = 0; k < 16; ++k) {
    const float f = t[sb + k][c];
    hbuf[k] = f2bf(f);
    lbuf[k] = f2bf(f - bf2f(hbuf[k]));
  }
  *(u16x8*)(xthi + tbase) = *(const u16x8*)&hbuf[0];
  *(u16x8*)(xthi + tbase + 8) = *(const u16x8*)&hbuf[8];
  *(u16x8*)(xtlo + tbase) = *(const u16x8*)&lbuf[0];
  *(u16x8*)(xtlo + tbase + 8) = *(const u16x8*)&lbuf[8];
}

// ---------- transpose + split weights: dst[n][k] = W[k][n] ----------
// z=0: Wq (hi+lo), z=1: Wv (hi), z=2: Wo (hi)
__global__ __launch_bounds__(256) void split_w_kernel(
    const float* __restrict__ Wq, const float* __restrict__ Wv,
    const float* __restrict__ Wo, unsigned short* qh, unsigned short* ql,
    unsigned short* vh, unsigned short* oh) {
  const float* W; unsigned short* dh; unsigned short* dl;
  if (blockIdx.z == 0)      { W = Wq; dh = qh; dl = ql; }
  else if (blockIdx.z == 1) { W = Wv; dh = vh; dl = nullptr; }
  else                      { W = Wo; dh = oh; dl = nullptr; }
  __shared__ float t[32][33];
  const int tx = threadIdx.x & 31, ty = threadIdx.x >> 5;
  const int c0 = blockIdx.x * 32, r0 = blockIdx.y * 32;
#pragma unroll
  for (int i = 0; i < 32; i += 8)
    t[ty + i][tx] = W[(size_t)(r0 + ty + i) * HID + c0 + tx];
  __syncthreads();
#pragma unroll
  for (int i = 0; i < 32; i += 8) {
    const float f = t[tx][ty + i];  // = W[r0+tx][c0+ty+i]
    const size_t di = (size_t)(c0 + ty + i) * HID + (r0 + tx);
    const unsigned short hb = f2bf(f);
    dh[di] = hb;
    if (dl) dl[di] = f2bf(f - bf2f(hb));
  }
}

// ---------- GEMM: C[z] = A[z] @ B^T-layout (B stored [N][K], shared over z) ----------
// SPLIT3: acc = A1*B1 + A1*B2 + A2*B1 (hi/lo split precision)
template <bool SPLIT3, bool OUT_BF16, bool BIAS>
__global__ __launch_bounds__(256, 2) void gemm_kernel(
    const unsigned short* __restrict__ A1, const unsigned short* __restrict__ A2,
    const unsigned short* __restrict__ B1, const unsigned short* __restrict__ B2,
    float* __restrict__ Cf, unsigned short* __restrict__ Cb,
    const float* __restrict__ bias, int M, int N, int Kd) {
  constexpr int TILE = 128 * 32;
  constexpr int NT = SPLIT3 ? 4 : 2;
  __shared__ unsigned short lds[NT * TILE];
  unsigned short* As1 = lds;
  unsigned short* Bs1 = lds + TILE;
  unsigned short* As2 = SPLIT3 ? lds + 2 * TILE : nullptr;
  unsigned short* Bs2 = SPLIT3 ? lds + 3 * TILE : nullptr;

  const int tid = threadIdx.x;
  const int lane = tid & 63;
  const int w = tid >> 6;
  const int wr = w >> 1, wc = w & 1;
  const int m0 = blockIdx.x * 128, n0 = blockIdx.y * 128;
  const int z = blockIdx.z;

  const unsigned short* pA1 = A1 + (size_t)z * M * Kd;
  const unsigned short* pA2 = SPLIT3 ? A2 + (size_t)z * M * Kd : nullptr;

  f32x4 acc[4][4] = {};
  const int fr = lane & 15;
  const int k8 = (lane >> 4) * 8;

  for (int kt = 0; kt < Kd; kt += 32) {
#pragma unroll
    for (int i = 0; i < 2; ++i) {
      const int ob = i * 4096 + tid * 16;
      const int r = ob >> 6;
      const int ce = (ob & 63) >> 1;
      gload16(pA1 + (size_t)(m0 + r) * Kd + kt + ce, (char*)As1 + ob);
      gload16(B1 + (size_t)(n0 + r) * Kd + kt + ce, (char*)Bs1 + ob);
      if (SPLIT3) {
        gload16(pA2 + (size_t)(m0 + r) * Kd + kt + ce, (char*)As2 + ob);
        gload16(B2 + (size_t)(n0 + r) * Kd + kt + ce, (char*)Bs2 + ob);
      }
    }
    __syncthreads();
    bf16x8 a1[4], b1[4], a2[4], b2[4];
#pragma unroll
    for (int m = 0; m < 4; ++m) {
      const int row = wr * 64 + m * 16 + fr;
      a1[m] = *(const bf16x8*)&As1[row * 32 + k8];
      if (SPLIT3) a2[m] = *(const bf16x8*)&As2[row * 32 + k8];
    }
#pragma unroll
    for (int n = 0; n < 4; ++n) {
      const int row = wc * 64 + n * 16 + fr;
      b1[n] = *(const bf16x8*)&Bs1[row * 32 + k8];
      if (SPLIT3) b2[n] = *(const bf16x8*)&Bs2[row * 32 + k8];
    }
#pragma unroll
    for (int m = 0; m < 4; ++m)
#pragma unroll
      for (int n = 0; n < 4; ++n) {
        acc[m][n] = __builtin_amdgcn_mfma_f32_16x16x32_bf16(a1[m], b1[n], acc[m][n], 0, 0, 0);
        if (SPLIT3) {
          acc[m][n] = __builtin_amdgcn_mfma_f32_16x16x32_bf16(a1[m], b2[n], acc[m][n], 0, 0, 0);
          acc[m][n] = __builtin_amdgcn_mfma_f32_16x16x32_bf16(a2[m], b1[n], acc[m][n], 0, 0, 0);
        }
      }
    __syncthreads();
  }

  const int r4 = (lane >> 4) * 4;
#pragma unroll
  for (int m = 0; m < 4; ++m) {
    const int row0 = m0 + wr * 64 + m * 16 + r4;
#pragma unroll
    for (int n = 0; n < 4; ++n) {
      const int col = n0 + wc * 64 + n * 16 + fr;
      const float bv = BIAS ? bias[col] : 0.0f;
#pragma unroll
      for (int r2 = 0; r2 < 4; ++r2) {
        const size_t idx = (size_t)z * M * N + (size_t)(row0 + r2) * N + col;
        const float vv = acc[m][n][r2] + bv;
        if (OUT_BF16) Cb[idx] = f2bf(vv);
        else Cf[idx] = vv;
      }
    }
  }
}

// ---------- Gram (triangular): lower-tri 128-blocks of G = Xt @ Xt^T, split3 ----------
// blockIdx.x in [0,36) -> (rb,cb) with cb<=rb; blockIdx.z = nb*3 + chunk (K-split 3)
// K-chunk boundaries MUST be multiples of 32 (BK): 0 / 1376 / 2752 / 4096.
__global__ __launch_bounds__(256, 2) void gram_kernel(
    const unsigned short* __restrict__ Xthi, const unsigned short* __restrict__ Xtlo,
    float* __restrict__ Gpart) {
  constexpr int TILE = 128 * 32;
  __shared__ unsigned short lds[4 * TILE];
  unsigned short* As1 = lds;
  unsigned short* Bs1 = lds + TILE;
  unsigned short* As2 = lds + 2 * TILE;
  unsigned short* Bs2 = lds + 3 * TILE;

  const int tid = threadIdx.x;
  const int lane = tid & 63;
  const int w = tid >> 6;
  const int wr = w >> 1, wc = w & 1;

  int rb = 0;
  {
    const int t = blockIdx.x;
    while ((rb + 1) * (rb + 2) / 2 <= t) ++rb;
  }
  const int cb = blockIdx.x - rb * (rb + 1) / 2;
  const int m0 = rb * 128, n0 = cb * 128;
  const int nb = blockIdx.z / 3, chunk = blockIdx.z % 3;
  const int kbeg = (chunk == 0) ? 0 : (chunk == 1 ? 1376 : 2752);
  const int kend = (chunk == 0) ? 1376 : (chunk == 1 ? 2752 : 4096);

  const size_t abase = (size_t)nb * HID * SEQ;
  const unsigned short* pH = Xthi + abase;  // row stride SEQ
  const unsigned short* pL = Xtlo + abase;

  f32x4 acc[4][4] = {};
  const int fr = lane & 15;
  const int k8 = (lane >> 4) * 8;

  for (int kt = kbeg; kt < kend; kt += 32) {
#pragma unroll
    for (int i = 0; i < 2; ++i) {
      const int ob = i * 4096 + tid * 16;
      const int r = ob >> 6;
      const int ce = (ob & 63) >> 1;
      gload16(pH + (size_t)(m0 + r) * SEQ + kt + ce, (char*)As1 + ob);
      gload16(pH + (size_t)(n0 + r) * SEQ + kt + ce, (char*)Bs1 + ob);
      gload16(pL + (size_t)(m0 + r) * SEQ + kt + ce, (char*)As2 + ob);
      gload16(pL + (size_t)(n0 + r) * SEQ + kt + ce, (char*)Bs2 + ob);
    }
    __syncthreads();
    bf16x8 a1[4], b1[4], a2[4], b2[4];
#pragma unroll
    for (int m = 0; m < 4; ++m) {
      const int row = wr * 64 + m * 16 + fr;
      a1[m] = *(const bf16x8*)&As1[row * 32 + k8];
      a2[m] = *(const bf16x8*)&As2[row * 32 + k8];
    }
#pragma unroll
    for (int n = 0; n < 4; ++n) {
      const int row = wc * 64 + n * 16 + fr;
      b1[n] = *(const bf16x8*)&Bs1[row * 32 + k8];
      b2[n] = *(const bf16x8*)&Bs2[row * 32 + k8];
    }
#pragma unroll
    for (int m = 0; m < 4; ++m)
#pragma unroll
      for (int n = 0; n < 4; ++n) {
        acc[m][n] = __builtin_amdgcn_mfma_f32_16x16x32_bf16(a1[m], b1[n], acc[m][n], 0, 0, 0);
        acc[m][n] = __builtin_amdgcn_mfma_f32_16x16x32_bf16(a1[m], b2[n], acc[m][n], 0, 0, 0);
        acc[m][n] = __builtin_amdgcn_mfma_f32_16x16x32_bf16(a2[m], b1[n], acc[m][n], 0, 0, 0);
      }
    __syncthreads();
  }

  float* Cf = Gpart + ((size_t)chunk * NBATCH + nb) * HID * HID;
  const int r4 = (lane >> 4) * 4;
#pragma unroll
  for (int m = 0; m < 4; ++m) {
    const int row0 = m0 + wr * 64 + m * 16 + r4;
#pragma unroll
    for (int n = 0; n < 4; ++n) {
      const int col = n0 + wc * 64 + n * 16 + fr;
#pragma unroll
      for (int r2 = 0; r2 < 4; ++r2)
        Cf[(size_t)(row0 + r2) * HID + col] = acc[m][n][r2];
    }
  }
}

// ---------- reduce 3 K-partials, mirror upper-tri 128-blocks, split hi/lo ----------
// grid (16,16,NBATCH): 64x64 tile (blockIdx.x=col-tile, .y=row-tile)
__global__ __launch_bounds__(256) void reduce_split_kernel(
    const float* __restrict__ Gp, unsigned short* __restrict__ ghi,
    unsigned short* __restrict__ glo) {
  const int nb = blockIdx.z;
  const int rt = blockIdx.y, ct = blockIdx.x;
  const size_t HH = (size_t)HID * HID;
  const float* g0 = Gp + (size_t)nb * HH;
  const float* g1 = g0 + (size_t)NBATCH * HH;
  const float* g2 = g1 + (size_t)NBATCH * HH;
  unsigned short* oh = ghi + (size_t)nb * HH;
  unsigned short* ol = glo + (size_t)nb * HH;
  const int tid = threadIdx.x;
  const int rr = tid >> 4, cc = (tid & 15) * 4;
  const bool mirrored = (rt >> 1) < (ct >> 1);  // strictly-upper 128-block
  __shared__ float t[64][65];

  if (!mirrored) {
#pragma unroll
    for (int p = 0; p < 4; ++p) {
      const size_t idx = (size_t)(rt * 64 + rr + p * 16) * HID + ct * 64 + cc;
      const float4 a = *(const float4*)(g0 + idx);
      const float4 b = *(const float4*)(g1 + idx);
      const float4 cv = *(const float4*)(g2 + idx);
      const float f[4] = {a.x + b.x + cv.x, a.y + b.y + cv.y,
                          a.z + b.z + cv.z, a.w + b.w + cv.w};
      ushort4 h, l;
      unsigned short hh[4], ll[4];
#pragma unroll
      for (int j = 0; j < 4; ++j) {
        hh[j] = f2bf(f[j]);
        ll[j] = f2bf(f[j] - bf2f(hh[j]));
      }
      h.x = hh[0]; h.y = hh[1]; h.z = hh[2]; h.w = hh[3];
      l.x = ll[0]; l.y = ll[1]; l.z = ll[2]; l.w = ll[3];
      *(ushort4*)(oh + idx) = h;
      *(ushort4*)(ol + idx) = l;
    }
  } else {
    // read the mirror (lower) tile coalesced, transpose via LDS
#pragma unroll
    for (int p = 0; p < 4; ++p) {
      const int lr = rr + p * 16;
      const size_t idx = (size_t)(ct * 64 + lr) * HID + rt * 64 + cc;
      const float4 a = *(const float4*)(g0 + idx);
      const float4 b = *(const float4*)(g1 + idx);
      const float4 cv = *(const float4*)(g2 + idx);
      t[lr][cc]     = a.x + b.x + cv.x;
      t[lr][cc + 1] = a.y + b.y + cv.y;
      t[lr][cc + 2] = a.z + b.z + cv.z;
      t[lr][cc + 3] = a.w + b.w + cv.w;
    }
    __syncthreads();
#pragma unroll
    for (int p = 0; p < 4; ++p) {
      const int orow = rr + p * 16;
      const size_t idx = (size_t)(rt * 64 + orow) * HID + ct * 64 + cc;
      ushort4 h, l;
      unsigned short hh[4], ll[4];
#pragma unroll
      for (int j = 0; j < 4; ++j) {
        const float f = t[cc + j][orow];  // G[r][c] = G[c][r]
        hh[j] = f2bf(f);
        ll[j] = f2bf(f - bf2f(hh[j]));
      }
      h.x = hh[0]; h.y = hh[1]; h.z = hh[2]; h.w = hh[3];
      l.x = ll[0]; l.y = ll[1]; l.z = ll[2]; l.w = ll[3];
      *(ushort4*)(oh + idx) = h;
      *(ushort4*)(ol + idx) = l;
    }
  }
}

// ---------- energy-style reduction: E[n,a,b] = sum_{r,d} Q[n,r,a*64+d]*K[n,r,b*64+d] ----------
__global__ __launch_bounds__(256) void energy_kernel(
    const float* __restrict__ Q, const float* __restrict__ Kq,
    float* __restrict__ energy, size_t qstride, size_t kstride) {
  const int n = blockIdx.y;
  const int s0 = blockIdx.x * 32;
  __shared__ float qs[16 * 68];
  __shared__ float ks[16 * 68];
  const int tid = threadIdx.x;
  const int a = tid >> 4, b = tid & 15;
  const int hb = (tid * 4) >> 6, d0 = (tid * 4) & 63;
  const float* Qn = Q + (size_t)n * qstride;
  const float* Kn = Kq + (size_t)n * kstride;
  float acc = 0.0f;
  for (int s = s0; s < s0 + 32; ++s) {
    __syncthreads();
    const float4 q4 = ((const float4*)(Qn + (size_t)s * HID))[tid];
    const float4 k4 = ((const float4*)(Kn + (size_t)s * HID))[tid];
    float* qp = qs + hb * 68 + d0;
    qp[0] = q4.x; qp[1] = q4.y; qp[2] = q4.z; qp[3] = q4.w;
    float* kp = ks + hb * 68 + d0;
    kp[0] = k4.x; kp[1] = k4.y; kp[2] = k4.z; kp[3] = k4.w;
    __syncthreads();
    float dot = 0.0f;
#pragma unroll
    for (int d = 0; d < 64; ++d) dot += qs[a * 68 + d] * ks[b * 68 + d];
    acc += dot;
  }
  atomicAdd(&energy[n * 256 + a * 16 + b], acc);
}

// ---------- softmax over b for each (n,a) row of 16 ----------
__global__ void softmax_kernel(const float* __restrict__ energy,
                               float* __restrict__ att) {
  const int t = threadIdx.x;  // 64 threads = (n,a)
  const float* e = energy + t * 16;
  float m = -3.0e38f;
#pragma unroll
  for (int b = 0; b < 16; ++b) m = fmaxf(m, e[b]);
  float p[16];
  float ssum = 0.0f;
#pragma unroll
  for (int b = 0; b < 16; ++b) { p[b] = expf((e[b] - m) * 0.125f); ssum += p[b]; }
  const float inv = 1.0f / ssum;
#pragma unroll
  for (int b = 0; b < 16; ++b) att[t * 16 + b] = p[b] * inv;
}

// ---------- out2[n, h*256+sg, r*64+d] = sum_b att[n,h,b] V[n, sg*16+r, b*64+d] ----------
__global__ __launch_bounds__(256) void out2_kernel(
    const unsigned short* __restrict__ V, const float* __restrict__ att,
    unsigned short* __restrict__ out2) {
  const int n = blockIdx.y, sg = blockIdx.x;
  __shared__ unsigned short vl[16 * 1032];
  __shared__ float al[256];
  const int tid = threadIdx.x;
  al[tid] = att[n * 256 + tid];
  const unsigned short* Vbp = V + ((size_t)n * SEQ + (size_t)sg * 16) * HID;
#pragma unroll
  for (int j = 0; j < 16; ++j) {
    const ushort4 u = *(const ushort4*)(Vbp + (size_t)j * HID + tid * 4);
    *(ushort4*)&vl[j * 1032 + tid * 4] = u;
  }
  __syncthreads();
  const int c0 = tid * 4;
  const int rr = c0 >> 6, d = c0 & 63;
  float vb[16][4];
#pragma unroll
  for (int b = 0; b < 16; ++b)
#pragma unroll
    for (int j = 0; j < 4; ++j)
      vb[b][j] = bf2f(vl[rr * 1032 + b * 64 + d + j]);
#pragma unroll
  for (int h = 0; h < 16; ++h) {
    float o0 = 0, o1 = 0, o2 = 0, o3 = 0;
#pragma unroll
    for (int b = 0; b < 16; ++b) {
      const float wgt = al[h * 16 + b];
      o0 += wgt * vb[b][0]; o1 += wgt * vb[b][1];
      o2 += wgt * vb[b][2]; o3 += wgt * vb[b][3];
    }
    ushort4 u;
    u.x = f2bf(o0); u.y = f2bf(o1); u.z = f2bf(o2); u.w = f2bf(o3);
    *(ushort4*)(out2 + ((size_t)n * SEQ + (size_t)(h * 256 + sg)) * HID + c0) = u;
  }
}

extern "C" void kernel_launch(void* const* d_in, const int* in_sizes, int n_in,
                              void* d_out, int out_size, void* d_ws, size_t ws_size,
                              hipStream_t stream) {
  (void)in_sizes; (void)n_in; (void)out_size; (void)ws_size;
  const float* x  = (const float*)d_in[0];
  const float* Wq = (const float*)d_in[1];
  const float* Wk = (const float*)d_in[2];
  const float* Wv = (const float*)d_in[3];
  const float* Wo = (const float*)d_in[4];
  const float* bo = (const float*)d_in[5];
  float* out = (float*)d_out;

  char* ws = (char*)d_ws;
  size_t off = 0;
  auto alloc = [&](size_t bytes) {
    char* p = ws + off;
    off += (bytes + 255) & ~(size_t)255;
    return p;
  };
  const size_t XE = (size_t)NBATCH * SEQ * HID;   // 16.8M elems
  const size_t GE = (size_t)NBATCH * HID * HID;   // 4.2M elems
  unsigned short* Xhi  = (unsigned short*)alloc(XE * 2);
  unsigned short* Xthi = (unsigned short*)alloc(XE * 2);  // -> Vb later
  unsigned short* Xtlo = (unsigned short*)alloc(XE * 2);  // -> O2 later
  unsigned short* WqhT = (unsigned short*)alloc((size_t)HID * HID * 2);
  unsigned short* WqlT = (unsigned short*)alloc((size_t)HID * HID * 2);
  unsigned short* WvhT = (unsigned short*)alloc((size_t)HID * HID * 2);
  unsigned short* WohT = (unsigned short*)alloc((size_t)HID * HID * 2);
  float* Gpart = (float*)alloc(3 * GE * 4);               // K-split x3 (-> M1 later)
  unsigned short* Ghi = (unsigned short*)alloc(GE * 2);
  unsigned short* Glo = (unsigned short*)alloc(GE * 2);
  float* energy = (float*)alloc((size_t)NBATCH * 256 * 4);
  float* att    = (float*)alloc((size_t)NBATCH * 256 * 4);
  // Stream-order-safe aliases:
  //   Vb overlays Xthi (last read: gram). M1 overlays Gpart (last read: reduce_split).
  //   O2 overlays Xtlo (last read: gram).
  unsigned short* Vb = Xthi;
  float* M1 = Gpart;
  unsigned short* O2 = Xtlo;

  split_x_kernel<<<dim3(HID / 64, SEQ / 64, NBATCH), 256, 0, stream>>>(
      x, Xhi, Xthi, Xtlo);
  split_w_kernel<<<dim3(HID / 32, HID / 32, 3), 256, 0, stream>>>(
      Wq, Wv, Wo, WqhT, WqlT, WvhT, WohT);

  // G = X^T X per batch: 36 lower-tri tiles x 4 batches x K-split 3 = 432 blocks
  gram_kernel<<<dim3(36, 1, NBATCH * 3), 256, 0, stream>>>(Xthi, Xtlo, Gpart);
  reduce_split_kernel<<<dim3(16, 16, NBATCH), 256, 0, stream>>>(Gpart, Ghi, Glo);

  // V = X @ Wv (plain bf16) — writes Vb (aliases Xthi, dead after gram)
  gemm_kernel<false, true, false><<<dim3(SEQ / 128, HID / 128, NBATCH), 256, 0, stream>>>(
      Xhi, nullptr, WvhT, nullptr, nullptr, Vb, nullptr, SEQ, HID, HID);

  // M1 = G @ Wq (split3)
  gemm_kernel<true, false, false><<<dim3(HID / 128, HID / 128, NBATCH), 256, 0, stream>>>(
      Ghi, Glo, WqhT, WqlT, M1, nullptr, nullptr, HID, HID, HID);

  // E[n,a,b] = sum_{k',d} M1[n,k',a64+d] * Wk[k',b64+d]
  hipMemsetAsync(energy, 0, (size_t)NBATCH * 256 * 4, stream);
  energy_kernel<<<dim3(HID / 32, NBATCH), 256, 0, stream>>>(
      M1, Wk, energy, (size_t)HID * HID, 0);
  softmax_kernel<<<1, 64, 0, stream>>>(energy, att);
  out2_kernel<<<dim3(256, NBATCH), 256, 0, stream>>>(Vb, att, O2);

  gemm_kernel<false, false, true><<<dim3(SEQ / 128, HID / 128, NBATCH), 256, 0, stream>>>(
      O2, nullptr, WohT, nullptr, out, nullptr, bo, SEQ, HID, HID);
}